// Round 12
// baseline (425.873 us; speedup 1.0000x reference)
//
#include <hip/hip_runtime.h>
#include <hip/hip_bf16.h>

#define N_NODES  100000
#define N_EDGES  640000
#define N_GRAPHS 2048
#define HID      128
#define NB_SCAN  391   // ceil(N_NODES/256)
#define TILE     64    // nodes per mm tile

typedef _Float16 half_t;
typedef __attribute__((ext_vector_type(4))) _Float16 half4;
typedef __attribute__((ext_vector_type(8))) _Float16 half8;
typedef __attribute__((ext_vector_type(4))) float floatx4;

// ---------------------------------------------------------------- degree
__global__ void k_deg(const int* __restrict__ col, int* __restrict__ deg) {
    int e = blockIdx.x * blockDim.x + threadIdx.x;
    if (e < N_EDGES) atomicAdd(&deg[col[e]], 1);
}

// ---------------------------------------------------------------- pack x rows to float4 (1 load/edge later)
__global__ void k_xpack(const float* __restrict__ x, float4* __restrict__ xp) {
    int i = blockIdx.x * 256 + threadIdx.x;
    if (i >= N_NODES) return;
    xp[i] = make_float4(x[i * 3 + 0], x[i * 3 + 1], x[i * 3 + 2], 0.f);
}

// ---------------------------------------------------------------- scan (exclusive prefix sum of deg -> row_ptr) + dinv
__global__ void k_scan1(const int* __restrict__ deg, int* __restrict__ row_ptr,
                        int* __restrict__ bsum, float* __restrict__ dinv) {
    __shared__ int s[256];
    int tid = threadIdx.x;
    int i = blockIdx.x * 256 + tid;
    int d = (i < N_NODES) ? deg[i] : 0;
    if (i < N_NODES) dinv[i] = rsqrtf((float)(d + 1));  // +1 self loop
    s[tid] = d;
    __syncthreads();
    for (int off = 1; off < 256; off <<= 1) {
        int v = (tid >= off) ? s[tid - off] : 0;
        __syncthreads();
        s[tid] += v;
        __syncthreads();
    }
    if (i < N_NODES) row_ptr[i] = s[tid] - d;   // exclusive within block
    if (tid == 255) bsum[blockIdx.x] = s[255];
}

__global__ void k_scan2(int* __restrict__ bsum) {
    __shared__ int s[512];
    int tid = threadIdx.x;
    int v = (tid < NB_SCAN) ? bsum[tid] : 0;
    s[tid] = v;
    __syncthreads();
    for (int off = 1; off < 512; off <<= 1) {
        int u = (tid >= off) ? s[tid - off] : 0;
        __syncthreads();
        s[tid] += u;
        __syncthreads();
    }
    if (tid < NB_SCAN) bsum[tid] = s[tid] - v;  // exclusive block offsets
}

__global__ void k_scan3(int* __restrict__ row_ptr, const int* __restrict__ bsum) {
    int i = blockIdx.x * 256 + threadIdx.x;
    if (i < N_NODES) row_ptr[i] += bsum[blockIdx.x];
    if (i == N_NODES) row_ptr[N_NODES] = N_EDGES;
}

// ---------------------------------------------------------------- CSR scatter
__global__ void k_scatter(const int* __restrict__ row, const int* __restrict__ col,
                          const int* __restrict__ row_ptr, int* __restrict__ cursor,
                          const float* __restrict__ dinv, int* __restrict__ src_idx,
                          float* __restrict__ w_edge) {
    int e = blockIdx.x * blockDim.x + threadIdx.x;
    if (e >= N_EDGES) return;
    int c = col[e];
    int r = row[e];
    int p = row_ptr[c] + atomicAdd(&cursor[c], 1);
    src_idx[p] = r;
    w_edge[p] = dinv[r] * dinv[c];
}

// ---------------------------------------------------------------- weight prep: Wt16[l][cout][cin] = (half)W_l[cin][cout]
__global__ void k_wcvt(const float* __restrict__ W2, const float* __restrict__ W3,
                       const float* __restrict__ W4, half_t* __restrict__ Wt) {
    int idx = blockIdx.x * 256 + threadIdx.x;
    if (idx >= 3 * 128 * 128) return;
    int l = idx >> 14;
    int e = idx & 16383;
    int cin = e >> 7, cout = e & 127;
    const float* W = (l == 0) ? W2 : ((l == 1) ? W3 : W4);
    Wt[l * 16384 + cout * 128 + cin] = (half_t)W[cin * 128 + cout];
}

// ---------------------------------------------------------------- aggregate x (packed float4), thread per node, 4-way unrolled
__global__ void k_aggx(const float4* __restrict__ xp, const int* __restrict__ row_ptr,
                       const int* __restrict__ src_idx, const float* __restrict__ w_edge,
                       const float* __restrict__ dinv, float* __restrict__ aggx) {
    int i = blockIdx.x * blockDim.x + threadIdx.x;
    if (i >= N_NODES) return;
    float di = dinv[i];
    float sw = di * di;
    float4 xv = xp[i];
    float a0 = sw * xv.x, a1 = sw * xv.y, a2 = sw * xv.z;
    int s = row_ptr[i], e = row_ptr[i + 1];
    int k = s;
    for (; k + 4 <= e; k += 4) {
        int j[4];
        float w[4];
#pragma unroll
        for (int r = 0; r < 4; r++) { j[r] = src_idx[k + r]; w[r] = w_edge[k + r]; }
        float4 bx[4];
#pragma unroll
        for (int r = 0; r < 4; r++) bx[r] = xp[j[r]];
#pragma unroll
        for (int r = 0; r < 4; r++) {
            a0 += w[r] * bx[r].x;
            a1 += w[r] * bx[r].y;
            a2 += w[r] * bx[r].z;
        }
    }
    for (; k < e; k++) {
        int j = src_idx[k];
        float w = w_edge[k];
        float4 bx = xp[j];
        a0 += w * bx.x;
        a1 += w * bx.y;
        a2 += w * bx.z;
    }
    aggx[i * 3 + 0] = a0;
    aggx[i * 3 + 1] = a1;
    aggx[i * 3 + 2] = a2;
}

// ---------------------------------------------------------------- layer-1 dense: aggx[N,3] @ W1[3,128] + b1, relu -> fp16
__global__ __launch_bounds__(256) void k_fc1(const float* __restrict__ aggx,
                                             const float* __restrict__ W1,
                                             const float* __restrict__ b1,
                                             half_t* __restrict__ h) {
    int idx = blockIdx.x * 256 + threadIdx.x;
    int node = idx >> 5;
    int cq = idx & 31;
    if (node >= N_NODES) return;
    float x0 = aggx[node * 3 + 0], x1 = aggx[node * 3 + 1], x2 = aggx[node * 3 + 2];
    const float4* W14 = (const float4*)W1;
    float4 w0 = W14[cq], w1 = W14[32 + cq], w2 = W14[64 + cq];
    float4 bb = ((const float4*)b1)[cq];
    half4 o;
    o.x = (half_t)fmaxf(bb.x + x0 * w0.x + x1 * w1.x + x2 * w2.x, 0.f);
    o.y = (half_t)fmaxf(bb.y + x0 * w0.y + x1 * w1.y + x2 * w2.y, 0.f);
    o.z = (half_t)fmaxf(bb.z + x0 * w0.z + x1 * w1.z + x2 * w2.z, 0.f);
    o.w = (half_t)fmaxf(bb.w + x0 * w0.w + x1 * w1.w + x2 * w2.w, 0.f);
    ((half4*)h)[(size_t)node * 32 + cq] = o;
}

// ---------------------------------------------------------------- LEAN standalone gather: g = Agg(h), fp16 rows
// 16 nodes/block (16 lanes x half8 = 256B row), serial edge loop with depth-2
// prefetch. No LDS, minimal VGPR -> waves-capped occupancy (32/CU).
__global__ __launch_bounds__(256, 8) void k_agg(const half_t* __restrict__ h_in,
                                                const int* __restrict__ row_ptr,
                                                const int* __restrict__ src_idx,
                                                const float* __restrict__ w_edge,
                                                const float* __restrict__ dinv,
                                                half_t* __restrict__ g) {
    int tid = threadIdx.x;
    int lane16 = tid & 15;
    int i = blockIdx.x * 16 + (tid >> 4);
    if (i >= N_NODES) return;
    const half8* h8 = (const half8*)h_in;

    float di = dinv[i];
    float sw = di * di;
    half8 v = h8[(size_t)i * 16 + lane16];
    float acc[8];
#pragma unroll
    for (int c = 0; c < 8; c++) acc[c] = sw * (float)v[c];

    int s = row_ptr[i], e = row_ptr[i + 1];
    if (s < e) {
        int jc = src_idx[s];
        float wc = w_edge[s];
        half8 ucur = h8[(size_t)jc * 16 + lane16];
        for (int k = s; k < e; k++) {
            int kn = (k + 1 < e) ? (k + 1) : k;
            int jn = src_idx[kn];
            float wn = (k + 1 < e) ? w_edge[kn] : 0.f;
            half8 un = h8[(size_t)jn * 16 + lane16];   // in flight while consuming ucur
#pragma unroll
            for (int c = 0; c < 8; c++) acc[c] += wc * (float)ucur[c];
            ucur = un; wc = wn;
        }
    }
    half8 av;
#pragma unroll
    for (int c = 0; c < 8; c++) av[c] = (half_t)acc[c];
    ((half8*)g)[(size_t)i * 16 + lane16] = av;
}

// ---------------------------------------------------------------- MFMA dense: h_out = relu(g @ W + b) (or pool)
// 64-node tile: cooperative 16KB load -> LDS -> mfma_f32_16x16x32_f16.
template <bool POOL>
__global__ __launch_bounds__(256) void k_mm(const half_t* __restrict__ g,
                                            const half_t* __restrict__ Wt,
                                            const float* __restrict__ b,
                                            half_t* __restrict__ h_out,
                                            const int* __restrict__ batch,
                                            float* __restrict__ pooled) {
    __shared__ half_t gs[TILE][128];  // 16 KB
    int tid = threadIdx.x;
    int n0 = blockIdx.x * TILE;

    // cooperative tile load: row = 128 halves = 256 B = 16 int4; 64 rows = 1024 int4
    const int4* gsrc = (const int4*)(g + (size_t)n0 * 128);
    int4* gdst = (int4*)&gs[0][0];
    for (int idx = tid; idx < TILE * 16; idx += 256) {
        int node = n0 + (idx >> 4);
        int4 vv;
        if (node < N_NODES) vv = gsrc[idx];
        else { vv.x = vv.y = vv.z = vv.w = 0; }
        gdst[idx] = vv;
    }
    __syncthreads();

    // MFMA 64x128x128: wave wv rows [wv*16,..+16); 8 N-tiles; K=128 in 4 steps
    int wv = tid >> 6;          // wave 0..3
    int ln = tid & 15;          // A-m / B-n / D-col
    int q  = (tid >> 4) & 3;    // quad
    floatx4 C[8];
#pragma unroll
    for (int t = 0; t < 8; t++) {
        float bn = b[t * 16 + ln];
        C[t].x = bn; C[t].y = bn; C[t].z = bn; C[t].w = bn;
    }
#pragma unroll
    for (int kq = 0; kq < 4; kq++) {
        half8 a = *(const half8*)(&gs[wv * 16 + ln][kq * 32 + q * 8]);
#pragma unroll
        for (int t = 0; t < 8; t++) {
            half8 bf = *(const half8*)(Wt + (size_t)(t * 16 + ln) * 128 + kq * 32 + q * 8);
            C[t] = __builtin_amdgcn_mfma_f32_16x16x32_f16(a, bf, C[t], 0, 0, 0);
        }
    }

    if (!POOL) {
        // stage relu(D) back into gs (wave-private rows), then coalesced write
        __syncthreads();
#pragma unroll
        for (int t = 0; t < 8; t++) {
#pragma unroll
            for (int reg = 0; reg < 4; reg++) {
                float dv = (reg == 0) ? C[t].x : (reg == 1) ? C[t].y : (reg == 2) ? C[t].z : C[t].w;
                gs[wv * 16 + q * 4 + reg][t * 16 + ln] = (half_t)fmaxf(dv, 0.f);
            }
        }
        __syncthreads();
        int r0 = tid >> 2;                 // row within tile
        int c0 = (tid & 3) * 4;            // int4 offset within row (row = 16 int4)
        int node = n0 + r0;
        if (node < N_NODES) {
            int4* dst = (int4*)(h_out + (size_t)node * 128);
            const int4* srcp = (const int4*)(&gs[r0][0]);
#pragma unroll
            for (int kk = 0; kk < 4; kk++) dst[c0 + kk] = srcp[c0 + kk];
        }
    } else {
        // run-length pool from C-layout: rows q*4+reg are consecutive sorted nodes
#pragma unroll
        for (int t = 0; t < 8; t++) {
            int ch = t * 16 + ln;
            int gcur = -1;
            float pa = 0.f;
#pragma unroll
            for (int reg = 0; reg < 4; reg++) {
                int node = n0 + wv * 16 + q * 4 + reg;
                if (node < N_NODES) {
                    float dv = (reg == 0) ? C[t].x : (reg == 1) ? C[t].y : (reg == 2) ? C[t].z : C[t].w;
                    dv = fmaxf(dv, 0.f);
                    int gb = batch[node];
                    if (gb != gcur) {
                        if (gcur >= 0) atomicAdd(&pooled[gcur * 128 + ch], pa);
                        gcur = gb; pa = 0.f;
                    }
                    pa += dv;
                }
            }
            if (gcur >= 0) atomicAdd(&pooled[gcur * 128 + ch], pa);
        }
    }
}

// ---------------------------------------------------------------- final FC: pooled[G,128]/cnt @ Wfc[128,4] + bfc
__global__ void k_final(const float* __restrict__ pooled, const int* __restrict__ batch,
                        const float* __restrict__ Wfc, const float* __restrict__ bfc,
                        float* __restrict__ out) {
    __shared__ float red[128][4];
    __shared__ int cnt_s;
    int g = blockIdx.x, t = threadIdx.x;
    if (t == 0) {
        int lo = 0, hi = N_NODES;
        while (lo < hi) { int mid = (lo + hi) >> 1; if (batch[mid] < g) lo = mid + 1; else hi = mid; }
        int s = lo;
        hi = N_NODES;
        while (lo < hi) { int mid = (lo + hi) >> 1; if (batch[mid] < g + 1) lo = mid + 1; else hi = mid; }
        cnt_s = lo - s;
    }
    __syncthreads();
    float inv = 1.0f / fmaxf((float)cnt_s, 1.0f);
    float v = pooled[g * 128 + t] * inv;
    float4 w = ((const float4*)Wfc)[t];
    red[t][0] = v * w.x; red[t][1] = v * w.y; red[t][2] = v * w.z; red[t][3] = v * w.w;
    __syncthreads();
    for (int s = 64; s > 0; s >>= 1) {
        if (t < s) {
            red[t][0] += red[t + s][0];
            red[t][1] += red[t + s][1];
            red[t][2] += red[t + s][2];
            red[t][3] += red[t + s][3];
        }
        __syncthreads();
    }
    if (t < 4) out[g * 4 + t] = red[0][t] + bfc[t];
}

// ================================================================ launch
extern "C" void kernel_launch(void* const* d_in, const int* in_sizes, int n_in,
                              void* d_out, int out_size, void* d_ws, size_t ws_size,
                              hipStream_t stream) {
    const float* x     = (const float*)d_in[0];
    const int*   ei    = (const int*)d_in[1];
    const int*   row   = ei;             // source
    const int*   col   = ei + N_EDGES;   // target (aggregation side)
    const int*   batch = (const int*)d_in[2];
    const float* W1 = (const float*)d_in[3];
    const float* b1 = (const float*)d_in[4];
    const float* W2 = (const float*)d_in[5];
    const float* b2 = (const float*)d_in[6];
    const float* W3 = (const float*)d_in[7];
    const float* b3 = (const float*)d_in[8];
    const float* W4 = (const float*)d_in[9];
    const float* b4 = (const float*)d_in[10];
    const float* Wfc = (const float*)d_in[11];
    const float* bfc = (const float*)d_in[12];
    float* out = (float*)d_out;

    char* ws = (char*)d_ws;
    size_t off = 0;
    auto take = [&](size_t bytes) -> char* {
        char* p = ws + off;
        off = (off + bytes + 255) & ~(size_t)255;
        return p;
    };
    // deg, cursor, pooled contiguous -> one memset
    int*    deg     = (int*)take(N_NODES * 4);
    int*    cursor  = (int*)take(N_NODES * 4);
    float*  pooled  = (float*)take((size_t)N_GRAPHS * 128 * 4);
    size_t  zspan   = (size_t)((char*)pooled + (size_t)N_GRAPHS * 128 * 4 - (char*)deg);
    int*    row_ptr = (int*)take((N_NODES + 1) * 4);
    int*    bsum    = (int*)take(512 * 4);
    float*  dinv    = (float*)take(N_NODES * 4);
    float*  aggx    = (float*)take((size_t)N_NODES * 3 * 4);
    float4* xp      = (float4*)take((size_t)N_NODES * 16);
    int*    src_idx = (int*)take(N_EDGES * 4);
    float*  w_edge  = (float*)take(N_EDGES * 4);
    half_t* wt16    = (half_t*)take((size_t)3 * 128 * 128 * 2);
    half_t* bufA    = (half_t*)take((size_t)N_NODES * 128 * 2);
    half_t* bufB    = (half_t*)take((size_t)N_NODES * 128 * 2);

    hipMemsetAsync(deg, 0, zspan, stream);

    k_deg<<<(N_EDGES + 255) / 256, 256, 0, stream>>>(col, deg);
    k_xpack<<<NB_SCAN, 256, 0, stream>>>(x, xp);
    k_wcvt<<<(3 * 128 * 128 + 255) / 256, 256, 0, stream>>>(W2, W3, W4, wt16);
    k_scan1<<<NB_SCAN, 256, 0, stream>>>(deg, row_ptr, bsum, dinv);
    k_scan2<<<1, 512, 0, stream>>>(bsum);
    k_scan3<<<NB_SCAN, 256, 0, stream>>>(row_ptr, bsum);
    k_scatter<<<(N_EDGES + 255) / 256, 256, 0, stream>>>(row, col, row_ptr, cursor,
                                                         dinv, src_idx, w_edge);
    k_aggx<<<NB_SCAN, 256, 0, stream>>>(xp, row_ptr, src_idx, w_edge, dinv, aggx);
    k_fc1<<<(N_NODES * 32 + 255) / 256, 256, 0, stream>>>(aggx, W1, b1, bufA);

    const int NBA = (N_NODES + 15) / 16;          // k_agg grid
    const int NBM = (N_NODES + TILE - 1) / TILE;  // k_mm grid
    // layer 2: agg(bufA)->bufB ; mm(bufB)->bufA
    k_agg<<<NBA, 256, 0, stream>>>(bufA, row_ptr, src_idx, w_edge, dinv, bufB);
    k_mm<false><<<NBM, 256, 0, stream>>>(bufB, wt16, b2, bufA, batch, pooled);
    // layer 3
    k_agg<<<NBA, 256, 0, stream>>>(bufA, row_ptr, src_idx, w_edge, dinv, bufB);
    k_mm<false><<<NBM, 256, 0, stream>>>(bufB, wt16 + 16384, b3, bufA, batch, pooled);
    // layer 4 (pool)
    k_agg<<<NBA, 256, 0, stream>>>(bufA, row_ptr, src_idx, w_edge, dinv, bufB);
    k_mm<true><<<NBM, 256, 0, stream>>>(bufB, wt16 + 32768, b4, nullptr, batch, pooled);

    k_final<<<N_GRAPHS, 128, 0, stream>>>(pooled, batch, Wfc, bfc, out);
}

// Round 13
// 420.079 us; speedup vs baseline: 1.0138x; 1.0138x over previous
//
#include <hip/hip_runtime.h>
#include <hip/hip_bf16.h>

#define N_NODES  100000
#define N_EDGES  640000
#define N_GRAPHS 2048
#define HID      128
#define NB_SCAN  391   // ceil(N_NODES/256)
#define TILE     64    // nodes per mm tile

typedef _Float16 half_t;
typedef __attribute__((ext_vector_type(4))) _Float16 half4;
typedef __attribute__((ext_vector_type(8))) _Float16 half8;
typedef __attribute__((ext_vector_type(4))) float floatx4;

// ---------------------------------------------------------------- degree
__global__ void k_deg(const int* __restrict__ col, int* __restrict__ deg) {
    int e = blockIdx.x * blockDim.x + threadIdx.x;
    if (e < N_EDGES) atomicAdd(&deg[col[e]], 1);
}

// ---------------------------------------------------------------- pack x rows to float4 (1 load/edge later)
__global__ void k_xpack(const float* __restrict__ x, float4* __restrict__ xp) {
    int i = blockIdx.x * 256 + threadIdx.x;
    if (i >= N_NODES) return;
    xp[i] = make_float4(x[i * 3 + 0], x[i * 3 + 1], x[i * 3 + 2], 0.f);
}

// ---------------------------------------------------------------- scan (exclusive prefix sum of deg -> row_ptr) + dinv
__global__ void k_scan1(const int* __restrict__ deg, int* __restrict__ row_ptr,
                        int* __restrict__ bsum, float* __restrict__ dinv) {
    __shared__ int s[256];
    int tid = threadIdx.x;
    int i = blockIdx.x * 256 + tid;
    int d = (i < N_NODES) ? deg[i] : 0;
    if (i < N_NODES) dinv[i] = rsqrtf((float)(d + 1));  // +1 self loop
    s[tid] = d;
    __syncthreads();
    for (int off = 1; off < 256; off <<= 1) {
        int v = (tid >= off) ? s[tid - off] : 0;
        __syncthreads();
        s[tid] += v;
        __syncthreads();
    }
    if (i < N_NODES) row_ptr[i] = s[tid] - d;   // exclusive within block
    if (tid == 255) bsum[blockIdx.x] = s[255];
}

__global__ void k_scan2(int* __restrict__ bsum) {
    __shared__ int s[512];
    int tid = threadIdx.x;
    int v = (tid < NB_SCAN) ? bsum[tid] : 0;
    s[tid] = v;
    __syncthreads();
    for (int off = 1; off < 512; off <<= 1) {
        int u = (tid >= off) ? s[tid - off] : 0;
        __syncthreads();
        s[tid] += u;
        __syncthreads();
    }
    if (tid < NB_SCAN) bsum[tid] = s[tid] - v;  // exclusive block offsets
}

__global__ void k_scan3(int* __restrict__ row_ptr, const int* __restrict__ bsum) {
    int i = blockIdx.x * 256 + threadIdx.x;
    if (i < N_NODES) row_ptr[i] += bsum[blockIdx.x];
    if (i == N_NODES) row_ptr[N_NODES] = N_EDGES;
}

// ---------------------------------------------------------------- CSR scatter
__global__ void k_scatter(const int* __restrict__ row, const int* __restrict__ col,
                          const int* __restrict__ row_ptr, int* __restrict__ cursor,
                          const float* __restrict__ dinv, int* __restrict__ src_idx,
                          float* __restrict__ w_edge) {
    int e = blockIdx.x * blockDim.x + threadIdx.x;
    if (e >= N_EDGES) return;
    int c = col[e];
    int r = row[e];
    int p = row_ptr[c] + atomicAdd(&cursor[c], 1);
    src_idx[p] = r;
    w_edge[p] = dinv[r] * dinv[c];
}

// ---------------------------------------------------------------- weight prep: Wt16[l][cout][cin] = (half)W_l[cin][cout]
__global__ void k_wcvt(const float* __restrict__ W2, const float* __restrict__ W3,
                       const float* __restrict__ W4, half_t* __restrict__ Wt) {
    int idx = blockIdx.x * 256 + threadIdx.x;
    if (idx >= 3 * 128 * 128) return;
    int l = idx >> 14;
    int e = idx & 16383;
    int cin = e >> 7, cout = e & 127;
    const float* W = (l == 0) ? W2 : ((l == 1) ? W3 : W4);
    Wt[l * 16384 + cout * 128 + cin] = (half_t)W[cin * 128 + cout];
}

// ---------------------------------------------------------------- aggregate x (packed float4), thread per node, 4-way unrolled
__global__ void k_aggx(const float4* __restrict__ xp, const int* __restrict__ row_ptr,
                       const int* __restrict__ src_idx, const float* __restrict__ w_edge,
                       const float* __restrict__ dinv, float* __restrict__ aggx) {
    int i = blockIdx.x * blockDim.x + threadIdx.x;
    if (i >= N_NODES) return;
    float di = dinv[i];
    float sw = di * di;
    float4 xv = xp[i];
    float a0 = sw * xv.x, a1 = sw * xv.y, a2 = sw * xv.z;
    int s = row_ptr[i], e = row_ptr[i + 1];
    int k = s;
    for (; k + 4 <= e; k += 4) {
        int j[4];
        float w[4];
#pragma unroll
        for (int r = 0; r < 4; r++) { j[r] = src_idx[k + r]; w[r] = w_edge[k + r]; }
        float4 bx[4];
#pragma unroll
        for (int r = 0; r < 4; r++) bx[r] = xp[j[r]];
#pragma unroll
        for (int r = 0; r < 4; r++) {
            a0 += w[r] * bx[r].x;
            a1 += w[r] * bx[r].y;
            a2 += w[r] * bx[r].z;
        }
    }
    for (; k < e; k++) {
        int j = src_idx[k];
        float w = w_edge[k];
        float4 bx = xp[j];
        a0 += w * bx.x;
        a1 += w * bx.y;
        a2 += w * bx.z;
    }
    aggx[i * 3 + 0] = a0;
    aggx[i * 3 + 1] = a1;
    aggx[i * 3 + 2] = a2;
}

// ---------------------------------------------------------------- layer-1 dense: aggx[N,3] @ W1[3,128] + b1, relu -> fp16
__global__ __launch_bounds__(256) void k_fc1(const float* __restrict__ aggx,
                                             const float* __restrict__ W1,
                                             const float* __restrict__ b1,
                                             half_t* __restrict__ h) {
    int idx = blockIdx.x * 256 + threadIdx.x;
    int node = idx >> 5;
    int cq = idx & 31;
    if (node >= N_NODES) return;
    float x0 = aggx[node * 3 + 0], x1 = aggx[node * 3 + 1], x2 = aggx[node * 3 + 2];
    const float4* W14 = (const float4*)W1;
    float4 w0 = W14[cq], w1 = W14[32 + cq], w2 = W14[64 + cq];
    float4 bb = ((const float4*)b1)[cq];
    half4 o;
    o.x = (half_t)fmaxf(bb.x + x0 * w0.x + x1 * w1.x + x2 * w2.x, 0.f);
    o.y = (half_t)fmaxf(bb.y + x0 * w0.y + x1 * w1.y + x2 * w2.y, 0.f);
    o.z = (half_t)fmaxf(bb.z + x0 * w0.z + x1 * w1.z + x2 * w2.z, 0.f);
    o.w = (half_t)fmaxf(bb.w + x0 * w0.w + x1 * w1.w + x2 * w2.w, 0.f);
    ((half4*)h)[(size_t)node * 32 + cq] = o;
}

// ---------------------------------------------------------------- LEAN standalone gather: g = Agg(h), fp16 rows
// 16 nodes/block (16 lanes x half8 = 256B row), serial edge loop with depth-2
// prefetch. No LDS, minimal VGPR -> waves-capped occupancy (32/CU).
__global__ __launch_bounds__(256, 8) void k_agg(const half_t* __restrict__ h_in,
                                                const int* __restrict__ row_ptr,
                                                const int* __restrict__ src_idx,
                                                const float* __restrict__ w_edge,
                                                const float* __restrict__ dinv,
                                                half_t* __restrict__ g) {
    int tid = threadIdx.x;
    int lane16 = tid & 15;
    int i = blockIdx.x * 16 + (tid >> 4);
    if (i >= N_NODES) return;
    const half8* h8 = (const half8*)h_in;

    float di = dinv[i];
    float sw = di * di;
    half8 v = h8[(size_t)i * 16 + lane16];
    float acc[8];
#pragma unroll
    for (int c = 0; c < 8; c++) acc[c] = sw * (float)v[c];

    int s = row_ptr[i], e = row_ptr[i + 1];
    if (s < e) {
        int jc = src_idx[s];
        float wc = w_edge[s];
        half8 ucur = h8[(size_t)jc * 16 + lane16];
        for (int k = s; k < e; k++) {
            int kn = (k + 1 < e) ? (k + 1) : k;
            int jn = src_idx[kn];
            float wn = (k + 1 < e) ? w_edge[kn] : 0.f;
            half8 un = h8[(size_t)jn * 16 + lane16];   // in flight while consuming ucur
#pragma unroll
            for (int c = 0; c < 8; c++) acc[c] += wc * (float)ucur[c];
            ucur = un; wc = wn;
        }
    }
    half8 av;
#pragma unroll
    for (int c = 0; c < 8; c++) av[c] = (half_t)acc[c];
    ((half8*)g)[(size_t)i * 16 + lane16] = av;
}

// ---------------------------------------------------------------- MFMA dense: h_out = relu(g @ W + b)
// 64-node tile: cooperative 16KB load -> LDS -> mfma_f32_16x16x32_f16.
__global__ __launch_bounds__(256) void k_mm(const half_t* __restrict__ g,
                                            const half_t* __restrict__ Wt,
                                            const float* __restrict__ b,
                                            half_t* __restrict__ h_out) {
    __shared__ half_t gs[TILE][128];  // 16 KB
    int tid = threadIdx.x;
    int n0 = blockIdx.x * TILE;

    // cooperative tile load: row = 128 halves = 256 B = 16 int4; 64 rows = 1024 int4
    const int4* gsrc = (const int4*)(g + (size_t)n0 * 128);
    int4* gdst = (int4*)&gs[0][0];
    for (int idx = tid; idx < TILE * 16; idx += 256) {
        int node = n0 + (idx >> 4);
        int4 vv;
        if (node < N_NODES) vv = gsrc[idx];
        else { vv.x = vv.y = vv.z = vv.w = 0; }
        gdst[idx] = vv;
    }
    __syncthreads();

    // MFMA 64x128x128: wave wv rows [wv*16,..+16); 8 N-tiles; K=128 in 4 steps
    int wv = tid >> 6;          // wave 0..3
    int ln = tid & 15;          // A-m / B-n / D-col
    int q  = (tid >> 4) & 3;    // quad
    floatx4 C[8];
#pragma unroll
    for (int t = 0; t < 8; t++) {
        float bn = b[t * 16 + ln];
        C[t].x = bn; C[t].y = bn; C[t].z = bn; C[t].w = bn;
    }
#pragma unroll
    for (int kq = 0; kq < 4; kq++) {
        half8 a = *(const half8*)(&gs[wv * 16 + ln][kq * 32 + q * 8]);
#pragma unroll
        for (int t = 0; t < 8; t++) {
            half8 bf = *(const half8*)(Wt + (size_t)(t * 16 + ln) * 128 + kq * 32 + q * 8);
            C[t] = __builtin_amdgcn_mfma_f32_16x16x32_f16(a, bf, C[t], 0, 0, 0);
        }
    }

    // stage relu(D) back into gs (wave-private rows), then coalesced write
    __syncthreads();
#pragma unroll
    for (int t = 0; t < 8; t++) {
#pragma unroll
        for (int reg = 0; reg < 4; reg++) {
            float dv = (reg == 0) ? C[t].x : (reg == 1) ? C[t].y : (reg == 2) ? C[t].z : C[t].w;
            gs[wv * 16 + q * 4 + reg][t * 16 + ln] = (half_t)fmaxf(dv, 0.f);
        }
    }
    __syncthreads();
    int r0 = tid >> 2;                 // row within tile
    int c0 = (tid & 3) * 4;            // int4 offset within row (row = 16 int4)
    int node = n0 + r0;
    if (node < N_NODES) {
        int4* dst = (int4*)(h_out + (size_t)node * 128);
        const int4* srcp = (const int4*)(&gs[r0][0]);
#pragma unroll
        for (int kk = 0; kk < 4; kk++) dst[c0 + kk] = srcp[c0 + kk];
    }
}

// ---------------------------------------------------------------- fused mean-pool + final FC (no atomics)
// block = graph g; binary search node range; accumulate fp16 rows (coalesced
// 256B/iter); divide by count; 128x4 FC via LDS reduction.
__global__ __launch_bounds__(128) void k_pool_final(const half_t* __restrict__ h,
                                                    const int* __restrict__ batch,
                                                    const float* __restrict__ Wfc,
                                                    const float* __restrict__ bfc,
                                                    float* __restrict__ out) {
    __shared__ float red[128][4];
    __shared__ int sb_s, eb_s;
    int g = blockIdx.x, t = threadIdx.x;
    if (t == 0) {
        int lo = 0, hi = N_NODES;
        while (lo < hi) { int mid = (lo + hi) >> 1; if (batch[mid] < g) lo = mid + 1; else hi = mid; }
        sb_s = lo;
        hi = N_NODES;
        while (lo < hi) { int mid = (lo + hi) >> 1; if (batch[mid] < g + 1) lo = mid + 1; else hi = mid; }
        eb_s = lo;
    }
    __syncthreads();
    int sb = sb_s, eb = eb_s;
    float acc = 0.f;
    for (int n = sb; n < eb; n++) {
        acc += (float)h[(size_t)n * 128 + t];    // coalesced 256B per iteration
    }
    float inv = 1.0f / fmaxf((float)(eb - sb), 1.0f);
    float v = acc * inv;
    float4 w = ((const float4*)Wfc)[t];
    red[t][0] = v * w.x; red[t][1] = v * w.y; red[t][2] = v * w.z; red[t][3] = v * w.w;
    __syncthreads();
    for (int s = 64; s > 0; s >>= 1) {
        if (t < s) {
            red[t][0] += red[t + s][0];
            red[t][1] += red[t + s][1];
            red[t][2] += red[t + s][2];
            red[t][3] += red[t + s][3];
        }
        __syncthreads();
    }
    if (t < 4) out[g * 4 + t] = red[0][t] + bfc[t];
}

// ================================================================ launch
extern "C" void kernel_launch(void* const* d_in, const int* in_sizes, int n_in,
                              void* d_out, int out_size, void* d_ws, size_t ws_size,
                              hipStream_t stream) {
    const float* x     = (const float*)d_in[0];
    const int*   ei    = (const int*)d_in[1];
    const int*   row   = ei;             // source
    const int*   col   = ei + N_EDGES;   // target (aggregation side)
    const int*   batch = (const int*)d_in[2];
    const float* W1 = (const float*)d_in[3];
    const float* b1 = (const float*)d_in[4];
    const float* W2 = (const float*)d_in[5];
    const float* b2 = (const float*)d_in[6];
    const float* W3 = (const float*)d_in[7];
    const float* b3 = (const float*)d_in[8];
    const float* W4 = (const float*)d_in[9];
    const float* b4 = (const float*)d_in[10];
    const float* Wfc = (const float*)d_in[11];
    const float* bfc = (const float*)d_in[12];
    float* out = (float*)d_out;

    char* ws = (char*)d_ws;
    size_t off = 0;
    auto take = [&](size_t bytes) -> char* {
        char* p = ws + off;
        off = (off + bytes + 255) & ~(size_t)255;
        return p;
    };
    // deg, cursor contiguous -> one memset
    int*    deg     = (int*)take(N_NODES * 4);
    int*    cursor  = (int*)take(N_NODES * 4);
    size_t  zspan   = (size_t)((char*)cursor + N_NODES * 4 - (char*)deg);
    int*    row_ptr = (int*)take((N_NODES + 1) * 4);
    int*    bsum    = (int*)take(512 * 4);
    float*  dinv    = (float*)take(N_NODES * 4);
    float*  aggx    = (float*)take((size_t)N_NODES * 3 * 4);
    float4* xp      = (float4*)take((size_t)N_NODES * 16);
    int*    src_idx = (int*)take(N_EDGES * 4);
    float*  w_edge  = (float*)take(N_EDGES * 4);
    half_t* wt16    = (half_t*)take((size_t)3 * 128 * 128 * 2);
    half_t* bufA    = (half_t*)take((size_t)N_NODES * 128 * 2);
    half_t* bufB    = (half_t*)take((size_t)N_NODES * 128 * 2);

    hipMemsetAsync(deg, 0, zspan, stream);

    k_deg<<<(N_EDGES + 255) / 256, 256, 0, stream>>>(col, deg);
    k_xpack<<<NB_SCAN, 256, 0, stream>>>(x, xp);
    k_wcvt<<<(3 * 128 * 128 + 255) / 256, 256, 0, stream>>>(W2, W3, W4, wt16);
    k_scan1<<<NB_SCAN, 256, 0, stream>>>(deg, row_ptr, bsum, dinv);
    k_scan2<<<1, 512, 0, stream>>>(bsum);
    k_scan3<<<NB_SCAN, 256, 0, stream>>>(row_ptr, bsum);
    k_scatter<<<(N_EDGES + 255) / 256, 256, 0, stream>>>(row, col, row_ptr, cursor,
                                                         dinv, src_idx, w_edge);
    k_aggx<<<NB_SCAN, 256, 0, stream>>>(xp, row_ptr, src_idx, w_edge, dinv, aggx);
    k_fc1<<<(N_NODES * 32 + 255) / 256, 256, 0, stream>>>(aggx, W1, b1, bufA);

    const int NBA = (N_NODES + 15) / 16;          // k_agg grid
    const int NBM = (N_NODES + TILE - 1) / TILE;  // k_mm grid
    // layer 2: agg(bufA)->bufB ; mm(bufB)->bufA
    k_agg<<<NBA, 256, 0, stream>>>(bufA, row_ptr, src_idx, w_edge, dinv, bufB);
    k_mm<<<NBM, 256, 0, stream>>>(bufB, wt16, b2, bufA);
    // layer 3
    k_agg<<<NBA, 256, 0, stream>>>(bufA, row_ptr, src_idx, w_edge, dinv, bufB);
    k_mm<<<NBM, 256, 0, stream>>>(bufB, wt16 + 16384, b3, bufA);
    // layer 4: agg(bufA)->bufB ; mm(bufB)->bufA (h4)
    k_agg<<<NBA, 256, 0, stream>>>(bufA, row_ptr, src_idx, w_edge, dinv, bufB);
    k_mm<<<NBM, 256, 0, stream>>>(bufB, wt16 + 32768, b4, bufA);

    // fused mean-pool + FC (no atomics)
    k_pool_final<<<N_GRAPHS, 128, 0, stream>>>(bufA, batch, Wfc, bfc, out);
}

// Round 14
// 393.246 us; speedup vs baseline: 1.0830x; 1.0682x over previous
//
#include <hip/hip_runtime.h>
#include <hip/hip_bf16.h>

#define N_NODES  100000
#define N_EDGES  640000
#define N_GRAPHS 2048
#define HID      128
#define NB_SCAN  391   // ceil(N_NODES/256)
#define TILE     64    // nodes per mm tile

typedef _Float16 half_t;
typedef __attribute__((ext_vector_type(4))) _Float16 half4;
typedef __attribute__((ext_vector_type(8))) _Float16 half8;
typedef __attribute__((ext_vector_type(4))) float floatx4;

// ---------------------------------------------------------------- fused prep: degree + x pack + weight convert
__global__ void k_prep(const int* __restrict__ col, int* __restrict__ deg,
                       const float* __restrict__ x, float4* __restrict__ xp,
                       const float* __restrict__ W2, const float* __restrict__ W3,
                       const float* __restrict__ W4, half_t* __restrict__ Wt) {
    int idx = blockIdx.x * 256 + threadIdx.x;
    if (idx < N_EDGES) atomicAdd(&deg[col[idx]], 1);
    if (idx < N_NODES) xp[idx] = make_float4(x[idx * 3 + 0], x[idx * 3 + 1], x[idx * 3 + 2], 0.f);
    if (idx < 3 * 128 * 128) {
        int l = idx >> 14;
        int e = idx & 16383;
        int cin = e >> 7, cout = e & 127;
        const float* W = (l == 0) ? W2 : ((l == 1) ? W3 : W4);
        Wt[l * 16384 + cout * 128 + cin] = (half_t)W[cin * 128 + cout];
    }
}

// ---------------------------------------------------------------- scan (exclusive prefix sum of deg -> row_ptr) + dinv
__global__ void k_scan1(const int* __restrict__ deg, int* __restrict__ row_ptr,
                        int* __restrict__ bsum, float* __restrict__ dinv) {
    __shared__ int s[256];
    int tid = threadIdx.x;
    int i = blockIdx.x * 256 + tid;
    int d = (i < N_NODES) ? deg[i] : 0;
    if (i < N_NODES) dinv[i] = rsqrtf((float)(d + 1));  // +1 self loop
    s[tid] = d;
    __syncthreads();
    for (int off = 1; off < 256; off <<= 1) {
        int v = (tid >= off) ? s[tid - off] : 0;
        __syncthreads();
        s[tid] += v;
        __syncthreads();
    }
    if (i < N_NODES) row_ptr[i] = s[tid] - d;   // exclusive within block
    if (tid == 255) bsum[blockIdx.x] = s[255];
}

__global__ void k_scan2(int* __restrict__ bsum) {
    __shared__ int s[512];
    int tid = threadIdx.x;
    int v = (tid < NB_SCAN) ? bsum[tid] : 0;
    s[tid] = v;
    __syncthreads();
    for (int off = 1; off < 512; off <<= 1) {
        int u = (tid >= off) ? s[tid - off] : 0;
        __syncthreads();
        s[tid] += u;
        __syncthreads();
    }
    if (tid < NB_SCAN) bsum[tid] = s[tid] - v;  // exclusive block offsets
}

__global__ void k_scan3(int* __restrict__ row_ptr, const int* __restrict__ bsum) {
    int i = blockIdx.x * 256 + threadIdx.x;
    if (i < N_NODES) row_ptr[i] += bsum[blockIdx.x];
    if (i == N_NODES) row_ptr[N_NODES] = N_EDGES;
}

// ---------------------------------------------------------------- CSR scatter
__global__ void k_scatter(const int* __restrict__ row, const int* __restrict__ col,
                          const int* __restrict__ row_ptr, int* __restrict__ cursor,
                          const float* __restrict__ dinv, int* __restrict__ src_idx,
                          float* __restrict__ w_edge) {
    int e = blockIdx.x * blockDim.x + threadIdx.x;
    if (e >= N_EDGES) return;
    int c = col[e];
    int r = row[e];
    int p = row_ptr[c] + atomicAdd(&cursor[c], 1);
    src_idx[p] = r;
    w_edge[p] = dinv[r] * dinv[c];
}

// ---------------------------------------------------------------- aggregate x (packed float4), thread per node, 4-way unrolled
__global__ void k_aggx(const float4* __restrict__ xp, const int* __restrict__ row_ptr,
                       const int* __restrict__ src_idx, const float* __restrict__ w_edge,
                       const float* __restrict__ dinv, float* __restrict__ aggx) {
    int i = blockIdx.x * blockDim.x + threadIdx.x;
    if (i >= N_NODES) return;
    float di = dinv[i];
    float sw = di * di;
    float4 xv = xp[i];
    float a0 = sw * xv.x, a1 = sw * xv.y, a2 = sw * xv.z;
    int s = row_ptr[i], e = row_ptr[i + 1];
    int k = s;
    for (; k + 4 <= e; k += 4) {
        int j[4];
        float w[4];
#pragma unroll
        for (int r = 0; r < 4; r++) { j[r] = src_idx[k + r]; w[r] = w_edge[k + r]; }
        float4 bx[4];
#pragma unroll
        for (int r = 0; r < 4; r++) bx[r] = xp[j[r]];
#pragma unroll
        for (int r = 0; r < 4; r++) {
            a0 += w[r] * bx[r].x;
            a1 += w[r] * bx[r].y;
            a2 += w[r] * bx[r].z;
        }
    }
    for (; k < e; k++) {
        int j = src_idx[k];
        float w = w_edge[k];
        float4 bx = xp[j];
        a0 += w * bx.x;
        a1 += w * bx.y;
        a2 += w * bx.z;
    }
    aggx[i * 3 + 0] = a0;
    aggx[i * 3 + 1] = a1;
    aggx[i * 3 + 2] = a2;
}

// ---------------------------------------------------------------- layer-1 dense: aggx[N,3] @ W1[3,128] + b1, relu -> fp16
__global__ __launch_bounds__(256) void k_fc1(const float* __restrict__ aggx,
                                             const float* __restrict__ W1,
                                             const float* __restrict__ b1,
                                             half_t* __restrict__ h) {
    int idx = blockIdx.x * 256 + threadIdx.x;
    int node = idx >> 5;
    int cq = idx & 31;
    if (node >= N_NODES) return;
    float x0 = aggx[node * 3 + 0], x1 = aggx[node * 3 + 1], x2 = aggx[node * 3 + 2];
    const float4* W14 = (const float4*)W1;
    float4 w0 = W14[cq], w1 = W14[32 + cq], w2 = W14[64 + cq];
    float4 bb = ((const float4*)b1)[cq];
    half4 o;
    o.x = (half_t)fmaxf(bb.x + x0 * w0.x + x1 * w1.x + x2 * w2.x, 0.f);
    o.y = (half_t)fmaxf(bb.y + x0 * w0.y + x1 * w1.y + x2 * w2.y, 0.f);
    o.z = (half_t)fmaxf(bb.z + x0 * w0.z + x1 * w1.z + x2 * w2.z, 0.f);
    o.w = (half_t)fmaxf(bb.w + x0 * w0.w + x1 * w1.w + x2 * w2.w, 0.f);
    ((half4*)h)[(size_t)node * 32 + cq] = o;
}

// ---------------------------------------------------------------- LEAN standalone gather: g = Agg(h), fp16 rows
// 16 nodes/block (16 lanes x half8 = 256B row). PAIRWISE edge loop with pair
// prefetch: 4 rows in flight per group (2 current + 2 next). Edge reads beyond
// the row end are clamped to e-1 (just-loaded -> L1 hit) with weight 0.
__global__ __launch_bounds__(256, 8) void k_agg(const half_t* __restrict__ h_in,
                                                const int* __restrict__ row_ptr,
                                                const int* __restrict__ src_idx,
                                                const float* __restrict__ w_edge,
                                                const float* __restrict__ dinv,
                                                half_t* __restrict__ g) {
    int tid = threadIdx.x;
    int lane16 = tid & 15;
    int i = blockIdx.x * 16 + (tid >> 4);
    if (i >= N_NODES) return;
    const half8* h8 = (const half8*)h_in;

    float di = dinv[i];
    float sw = di * di;
    half8 v = h8[(size_t)i * 16 + lane16];
    float acc[8];
#pragma unroll
    for (int c = 0; c < 8; c++) acc[c] = sw * (float)v[c];

    int s = row_ptr[i], e = row_ptr[i + 1];
    if (s < e) {
        int em1 = e - 1;
        int j0 = src_idx[s];
        float w0 = w_edge[s];
        int k1 = min(s + 1, em1);
        int j1 = src_idx[k1];
        float w1 = (s + 1 < e) ? w_edge[k1] : 0.f;
        half8 u0 = h8[(size_t)j0 * 16 + lane16];
        half8 u1 = h8[(size_t)j1 * 16 + lane16];
        for (int k = s; k < e; k += 2) {
            int k2 = min(k + 2, em1);
            int k3 = min(k + 3, em1);
            int j2 = src_idx[k2];
            int j3 = src_idx[k3];
            float w2 = (k + 2 < e) ? w_edge[k2] : 0.f;
            float w3 = (k + 3 < e) ? w_edge[k3] : 0.f;
            half8 n0 = h8[(size_t)j2 * 16 + lane16];   // next pair in flight
            half8 n1 = h8[(size_t)j3 * 16 + lane16];
#pragma unroll
            for (int c = 0; c < 8; c++) acc[c] += w0 * (float)u0[c] + w1 * (float)u1[c];
            u0 = n0; u1 = n1; w0 = w2; w1 = w3;
        }
    }
    half8 av;
#pragma unroll
    for (int c = 0; c < 8; c++) av[c] = (half_t)acc[c];
    ((half8*)g)[(size_t)i * 16 + lane16] = av;
}

// ---------------------------------------------------------------- MFMA dense: h_out = relu(g @ W + b)
// 64-node tile: cooperative 16KB load -> LDS -> mfma_f32_16x16x32_f16.
__global__ __launch_bounds__(256) void k_mm(const half_t* __restrict__ g,
                                            const half_t* __restrict__ Wt,
                                            const float* __restrict__ b,
                                            half_t* __restrict__ h_out) {
    __shared__ half_t gs[TILE][128];  // 16 KB
    int tid = threadIdx.x;
    int n0 = blockIdx.x * TILE;

    // cooperative tile load: row = 128 halves = 256 B = 16 int4; 64 rows = 1024 int4
    const int4* gsrc = (const int4*)(g + (size_t)n0 * 128);
    int4* gdst = (int4*)&gs[0][0];
    for (int idx = tid; idx < TILE * 16; idx += 256) {
        int node = n0 + (idx >> 4);
        int4 vv;
        if (node < N_NODES) vv = gsrc[idx];
        else { vv.x = vv.y = vv.z = vv.w = 0; }
        gdst[idx] = vv;
    }
    __syncthreads();

    // MFMA 64x128x128: wave wv rows [wv*16,..+16); 8 N-tiles; K=128 in 4 steps
    int wv = tid >> 6;          // wave 0..3
    int ln = tid & 15;          // A-m / B-n / D-col
    int q  = (tid >> 4) & 3;    // quad
    floatx4 C[8];
#pragma unroll
    for (int t = 0; t < 8; t++) {
        float bn = b[t * 16 + ln];
        C[t].x = bn; C[t].y = bn; C[t].z = bn; C[t].w = bn;
    }
#pragma unroll
    for (int kq = 0; kq < 4; kq++) {
        half8 a = *(const half8*)(&gs[wv * 16 + ln][kq * 32 + q * 8]);
#pragma unroll
        for (int t = 0; t < 8; t++) {
            half8 bf = *(const half8*)(Wt + (size_t)(t * 16 + ln) * 128 + kq * 32 + q * 8);
            C[t] = __builtin_amdgcn_mfma_f32_16x16x32_f16(a, bf, C[t], 0, 0, 0);
        }
    }

    // stage relu(D) back into gs (wave-private rows), then coalesced write
    __syncthreads();
#pragma unroll
    for (int t = 0; t < 8; t++) {
#pragma unroll
        for (int reg = 0; reg < 4; reg++) {
            float dv = (reg == 0) ? C[t].x : (reg == 1) ? C[t].y : (reg == 2) ? C[t].z : C[t].w;
            gs[wv * 16 + q * 4 + reg][t * 16 + ln] = (half_t)fmaxf(dv, 0.f);
        }
    }
    __syncthreads();
    int r0 = tid >> 2;                 // row within tile
    int c0 = (tid & 3) * 4;            // int4 offset within row (row = 16 int4)
    int node = n0 + r0;
    if (node < N_NODES) {
        int4* dst = (int4*)(h_out + (size_t)node * 128);
        const int4* srcp = (const int4*)(&gs[r0][0]);
#pragma unroll
        for (int kk = 0; kk < 4; kk++) dst[c0 + kk] = srcp[c0 + kk];
    }
}

// ---------------------------------------------------------------- fused mean-pool + final FC (no atomics)
// block = graph g; 4-way row unroll (4 independent loads in flight); then
// 128x4 FC via LDS reduction.
__global__ __launch_bounds__(128) void k_pool_final(const half_t* __restrict__ h,
                                                    const int* __restrict__ batch,
                                                    const float* __restrict__ Wfc,
                                                    const float* __restrict__ bfc,
                                                    float* __restrict__ out) {
    __shared__ float red[128][4];
    __shared__ int sb_s, eb_s;
    int g = blockIdx.x, t = threadIdx.x;
    if (t == 0) {
        int lo = 0, hi = N_NODES;
        while (lo < hi) { int mid = (lo + hi) >> 1; if (batch[mid] < g) lo = mid + 1; else hi = mid; }
        sb_s = lo;
        hi = N_NODES;
        while (lo < hi) { int mid = (lo + hi) >> 1; if (batch[mid] < g + 1) lo = mid + 1; else hi = mid; }
        eb_s = lo;
    }
    __syncthreads();
    int sb = sb_s, eb = eb_s;
    float a0 = 0.f, a1 = 0.f, a2 = 0.f, a3 = 0.f;
    int n = sb;
    for (; n + 4 <= eb; n += 4) {
        float v0 = (float)h[(size_t)(n + 0) * 128 + t];
        float v1 = (float)h[(size_t)(n + 1) * 128 + t];
        float v2 = (float)h[(size_t)(n + 2) * 128 + t];
        float v3 = (float)h[(size_t)(n + 3) * 128 + t];
        a0 += v0; a1 += v1; a2 += v2; a3 += v3;
    }
    for (; n < eb; n++) a0 += (float)h[(size_t)n * 128 + t];
    float acc = (a0 + a1) + (a2 + a3);
    float inv = 1.0f / fmaxf((float)(eb - sb), 1.0f);
    float v = acc * inv;
    float4 w = ((const float4*)Wfc)[t];
    red[t][0] = v * w.x; red[t][1] = v * w.y; red[t][2] = v * w.z; red[t][3] = v * w.w;
    __syncthreads();
    for (int s = 64; s > 0; s >>= 1) {
        if (t < s) {
            red[t][0] += red[t + s][0];
            red[t][1] += red[t + s][1];
            red[t][2] += red[t + s][2];
            red[t][3] += red[t + s][3];
        }
        __syncthreads();
    }
    if (t < 4) out[g * 4 + t] = red[0][t] + bfc[t];
}

// ================================================================ launch
extern "C" void kernel_launch(void* const* d_in, const int* in_sizes, int n_in,
                              void* d_out, int out_size, void* d_ws, size_t ws_size,
                              hipStream_t stream) {
    const float* x     = (const float*)d_in[0];
    const int*   ei    = (const int*)d_in[1];
    const int*   row   = ei;             // source
    const int*   col   = ei + N_EDGES;   // target (aggregation side)
    const int*   batch = (const int*)d_in[2];
    const float* W1 = (const float*)d_in[3];
    const float* b1 = (const float*)d_in[4];
    const float* W2 = (const float*)d_in[5];
    const float* b2 = (const float*)d_in[6];
    const float* W3 = (const float*)d_in[7];
    const float* b3 = (const float*)d_in[8];
    const float* W4 = (const float*)d_in[9];
    const float* b4 = (const float*)d_in[10];
    const float* Wfc = (const float*)d_in[11];
    const float* bfc = (const float*)d_in[12];
    float* out = (float*)d_out;

    char* ws = (char*)d_ws;
    size_t off = 0;
    auto take = [&](size_t bytes) -> char* {
        char* p = ws + off;
        off = (off + bytes + 255) & ~(size_t)255;
        return p;
    };
    // deg, cursor contiguous -> one memset
    int*    deg     = (int*)take(N_NODES * 4);
    int*    cursor  = (int*)take(N_NODES * 4);
    size_t  zspan   = (size_t)((char*)cursor + N_NODES * 4 - (char*)deg);
    int*    row_ptr = (int*)take((N_NODES + 1) * 4);
    int*    bsum    = (int*)take(512 * 4);
    float*  dinv    = (float*)take(N_NODES * 4);
    float*  aggx    = (float*)take((size_t)N_NODES * 3 * 4);
    float4* xp      = (float4*)take((size_t)N_NODES * 16);
    int*    src_idx = (int*)take(N_EDGES * 4);
    float*  w_edge  = (float*)take(N_EDGES * 4);
    half_t* wt16    = (half_t*)take((size_t)3 * 128 * 128 * 2);
    half_t* bufA    = (half_t*)take((size_t)N_NODES * 128 * 2);
    half_t* bufB    = (half_t*)take((size_t)N_NODES * 128 * 2);

    hipMemsetAsync(deg, 0, zspan, stream);

    k_prep<<<(N_EDGES + 255) / 256, 256, 0, stream>>>(col, deg, x, xp, W2, W3, W4, wt16);
    k_scan1<<<NB_SCAN, 256, 0, stream>>>(deg, row_ptr, bsum, dinv);
    k_scan2<<<1, 512, 0, stream>>>(bsum);
    k_scan3<<<NB_SCAN, 256, 0, stream>>>(row_ptr, bsum);
    k_scatter<<<(N_EDGES + 255) / 256, 256, 0, stream>>>(row, col, row_ptr, cursor,
                                                         dinv, src_idx, w_edge);
    k_aggx<<<NB_SCAN, 256, 0, stream>>>(xp, row_ptr, src_idx, w_edge, dinv, aggx);
    k_fc1<<<(N_NODES * 32 + 255) / 256, 256, 0, stream>>>(aggx, W1, b1, bufA);

    const int NBA = (N_NODES + 15) / 16;          // k_agg grid
    const int NBM = (N_NODES + TILE - 1) / TILE;  // k_mm grid
    // layer 2: agg(bufA)->bufB ; mm(bufB)->bufA
    k_agg<<<NBA, 256, 0, stream>>>(bufA, row_ptr, src_idx, w_edge, dinv, bufB);
    k_mm<<<NBM, 256, 0, stream>>>(bufB, wt16, b2, bufA);
    // layer 3
    k_agg<<<NBA, 256, 0, stream>>>(bufA, row_ptr, src_idx, w_edge, dinv, bufB);
    k_mm<<<NBM, 256, 0, stream>>>(bufB, wt16 + 16384, b3, bufA);
    // layer 4
    k_agg<<<NBA, 256, 0, stream>>>(bufA, row_ptr, src_idx, w_edge, dinv, bufB);
    k_mm<<<NBM, 256, 0, stream>>>(bufB, wt16 + 32768, b4, bufA);

    // fused mean-pool + FC (no atomics)
    k_pool_final<<<N_GRAPHS, 128, 0, stream>>>(bufA, batch, Wfc, bfc, out);
}

// Round 15
// 389.562 us; speedup vs baseline: 1.0932x; 1.0095x over previous
//
#include <hip/hip_runtime.h>
#include <hip/hip_bf16.h>

#define N_NODES  100000
#define N_EDGES  640000
#define N_GRAPHS 2048
#define HID      128
#define NB_SCAN  391   // ceil(N_NODES/256)
#define TILE     64    // nodes per mm tile

typedef _Float16 half_t;
typedef __attribute__((ext_vector_type(4))) _Float16 half4;
typedef __attribute__((ext_vector_type(8))) _Float16 half8;
typedef __attribute__((ext_vector_type(4))) float floatx4;

// ---------------------------------------------------------------- fused prep: degree + x pack + weight convert
__global__ void k_prep(const int* __restrict__ col, int* __restrict__ deg,
                       const float* __restrict__ x, float4* __restrict__ xp,
                       const float* __restrict__ W2, const float* __restrict__ W3,
                       const float* __restrict__ W4, half_t* __restrict__ Wt) {
    int idx = blockIdx.x * 256 + threadIdx.x;
    if (idx < N_EDGES) atomicAdd(&deg[col[idx]], 1);
    if (idx < N_NODES) xp[idx] = make_float4(x[idx * 3 + 0], x[idx * 3 + 1], x[idx * 3 + 2], 0.f);
    if (idx < 3 * 128 * 128) {
        int l = idx >> 14;
        int e = idx & 16383;
        int cin = e >> 7, cout = e & 127;
        const float* W = (l == 0) ? W2 : ((l == 1) ? W3 : W4);
        Wt[l * 16384 + cout * 128 + cin] = (half_t)W[cin * 128 + cout];
    }
}

// ---------------------------------------------------------------- scan (exclusive prefix sum of deg -> row_ptr) + dinv
__global__ void k_scan1(const int* __restrict__ deg, int* __restrict__ row_ptr,
                        int* __restrict__ bsum, float* __restrict__ dinv) {
    __shared__ int s[256];
    int tid = threadIdx.x;
    int i = blockIdx.x * 256 + tid;
    int d = (i < N_NODES) ? deg[i] : 0;
    if (i < N_NODES) dinv[i] = rsqrtf((float)(d + 1));  // +1 self loop
    s[tid] = d;
    __syncthreads();
    for (int off = 1; off < 256; off <<= 1) {
        int v = (tid >= off) ? s[tid - off] : 0;
        __syncthreads();
        s[tid] += v;
        __syncthreads();
    }
    if (i < N_NODES) row_ptr[i] = s[tid] - d;   // exclusive within block
    if (tid == 255) bsum[blockIdx.x] = s[255];
}

__global__ void k_scan2(int* __restrict__ bsum) {
    __shared__ int s[512];
    int tid = threadIdx.x;
    int v = (tid < NB_SCAN) ? bsum[tid] : 0;
    s[tid] = v;
    __syncthreads();
    for (int off = 1; off < 512; off <<= 1) {
        int u = (tid >= off) ? s[tid - off] : 0;
        __syncthreads();
        s[tid] += u;
        __syncthreads();
    }
    if (tid < NB_SCAN) bsum[tid] = s[tid] - v;  // exclusive block offsets
}

__global__ void k_scan3(int* __restrict__ row_ptr, const int* __restrict__ bsum) {
    int i = blockIdx.x * 256 + threadIdx.x;
    if (i < N_NODES) row_ptr[i] += bsum[blockIdx.x];
    if (i == N_NODES) row_ptr[N_NODES] = N_EDGES;
}

// ---------------------------------------------------------------- CSR scatter: packed (src, weight) int2 -> ONE 8B store
__global__ void k_scatter(const int* __restrict__ row, const int* __restrict__ col,
                          const int* __restrict__ row_ptr, int* __restrict__ cursor,
                          const float* __restrict__ dinv, int2* __restrict__ epair) {
    int e = blockIdx.x * blockDim.x + threadIdx.x;
    if (e >= N_EDGES) return;
    int c = col[e];
    int r = row[e];
    int p = row_ptr[c] + atomicAdd(&cursor[c], 1);
    epair[p] = make_int2(r, __float_as_int(dinv[r] * dinv[c]));
}

// ---------------------------------------------------------------- aggregate x (packed float4), thread per node, 4-way unrolled
__global__ void k_aggx(const float4* __restrict__ xp, const int* __restrict__ row_ptr,
                       const int2* __restrict__ epair, const float* __restrict__ dinv,
                       float* __restrict__ aggx) {
    int i = blockIdx.x * blockDim.x + threadIdx.x;
    if (i >= N_NODES) return;
    float di = dinv[i];
    float sw = di * di;
    float4 xv = xp[i];
    float a0 = sw * xv.x, a1 = sw * xv.y, a2 = sw * xv.z;
    int s = row_ptr[i], e = row_ptr[i + 1];
    int k = s;
    for (; k + 4 <= e; k += 4) {
        int2 pr[4];
#pragma unroll
        for (int r = 0; r < 4; r++) pr[r] = epair[k + r];
        float4 bx[4];
#pragma unroll
        for (int r = 0; r < 4; r++) bx[r] = xp[pr[r].x];
#pragma unroll
        for (int r = 0; r < 4; r++) {
            float w = __int_as_float(pr[r].y);
            a0 += w * bx[r].x;
            a1 += w * bx[r].y;
            a2 += w * bx[r].z;
        }
    }
    for (; k < e; k++) {
        int2 pr = epair[k];
        float w = __int_as_float(pr.y);
        float4 bx = xp[pr.x];
        a0 += w * bx.x;
        a1 += w * bx.y;
        a2 += w * bx.z;
    }
    aggx[i * 3 + 0] = a0;
    aggx[i * 3 + 1] = a1;
    aggx[i * 3 + 2] = a2;
}

// ---------------------------------------------------------------- layer-1 dense: aggx[N,3] @ W1[3,128] + b1, relu -> fp16
__global__ __launch_bounds__(256) void k_fc1(const float* __restrict__ aggx,
                                             const float* __restrict__ W1,
                                             const float* __restrict__ b1,
                                             half_t* __restrict__ h) {
    int idx = blockIdx.x * 256 + threadIdx.x;
    int node = idx >> 5;
    int cq = idx & 31;
    if (node >= N_NODES) return;
    float x0 = aggx[node * 3 + 0], x1 = aggx[node * 3 + 1], x2 = aggx[node * 3 + 2];
    const float4* W14 = (const float4*)W1;
    float4 w0 = W14[cq], w1 = W14[32 + cq], w2 = W14[64 + cq];
    float4 bb = ((const float4*)b1)[cq];
    half4 o;
    o.x = (half_t)fmaxf(bb.x + x0 * w0.x + x1 * w1.x + x2 * w2.x, 0.f);
    o.y = (half_t)fmaxf(bb.y + x0 * w0.y + x1 * w1.y + x2 * w2.y, 0.f);
    o.z = (half_t)fmaxf(bb.z + x0 * w0.z + x1 * w1.z + x2 * w2.z, 0.f);
    o.w = (half_t)fmaxf(bb.w + x0 * w0.w + x1 * w1.w + x2 * w2.w, 0.f);
    ((half4*)h)[(size_t)node * 32 + cq] = o;
}

// ---------------------------------------------------------------- LEAN standalone gather: g = Agg(h), fp16 rows
// 16 nodes/block (16 lanes x half8 = 256B row). Pairwise edge loop with pair
// prefetch (4 rows in flight per group). Edge metadata = packed int2 (one load
// per edge instead of two). OOB edges clamp to e-1 (L1 hit) with weight 0.
__global__ __launch_bounds__(256, 8) void k_agg(const half_t* __restrict__ h_in,
                                                const int* __restrict__ row_ptr,
                                                const int2* __restrict__ epair,
                                                const float* __restrict__ dinv,
                                                half_t* __restrict__ g) {
    int tid = threadIdx.x;
    int lane16 = tid & 15;
    int i = blockIdx.x * 16 + (tid >> 4);
    if (i >= N_NODES) return;
    const half8* h8 = (const half8*)h_in;

    float di = dinv[i];
    float sw = di * di;
    half8 v = h8[(size_t)i * 16 + lane16];
    float acc[8];
#pragma unroll
    for (int c = 0; c < 8; c++) acc[c] = sw * (float)v[c];

    int s = row_ptr[i], e = row_ptr[i + 1];
    if (s < e) {
        int em1 = e - 1;
        int2 p0 = epair[s];
        int k1 = min(s + 1, em1);
        int2 p1 = epair[k1];
        float w0 = __int_as_float(p0.y);
        float w1 = (s + 1 < e) ? __int_as_float(p1.y) : 0.f;
        half8 u0 = h8[(size_t)p0.x * 16 + lane16];
        half8 u1 = h8[(size_t)p1.x * 16 + lane16];
        for (int k = s; k < e; k += 2) {
            int k2 = min(k + 2, em1);
            int k3 = min(k + 3, em1);
            int2 p2 = epair[k2];
            int2 p3 = epair[k3];
            float w2 = (k + 2 < e) ? __int_as_float(p2.y) : 0.f;
            float w3 = (k + 3 < e) ? __int_as_float(p3.y) : 0.f;
            half8 n0 = h8[(size_t)p2.x * 16 + lane16];   // next pair in flight
            half8 n1 = h8[(size_t)p3.x * 16 + lane16];
#pragma unroll
            for (int c = 0; c < 8; c++) acc[c] += w0 * (float)u0[c] + w1 * (float)u1[c];
            u0 = n0; u1 = n1; w0 = w2; w1 = w3;
        }
    }
    half8 av;
#pragma unroll
    for (int c = 0; c < 8; c++) av[c] = (half_t)acc[c];
    ((half8*)g)[(size_t)i * 16 + lane16] = av;
}

// ---------------------------------------------------------------- MFMA dense: h_out = relu(g @ W + b)
// 64-node tile: cooperative 16KB load -> LDS -> mfma_f32_16x16x32_f16.
__global__ __launch_bounds__(256) void k_mm(const half_t* __restrict__ g,
                                            const half_t* __restrict__ Wt,
                                            const float* __restrict__ b,
                                            half_t* __restrict__ h_out) {
    __shared__ half_t gs[TILE][128];  // 16 KB
    int tid = threadIdx.x;
    int n0 = blockIdx.x * TILE;

    // cooperative tile load: row = 128 halves = 256 B = 16 int4; 64 rows = 1024 int4
    const int4* gsrc = (const int4*)(g + (size_t)n0 * 128);
    int4* gdst = (int4*)&gs[0][0];
    for (int idx = tid; idx < TILE * 16; idx += 256) {
        int node = n0 + (idx >> 4);
        int4 vv;
        if (node < N_NODES) vv = gsrc[idx];
        else { vv.x = vv.y = vv.z = vv.w = 0; }
        gdst[idx] = vv;
    }
    __syncthreads();

    // MFMA 64x128x128: wave wv rows [wv*16,..+16); 8 N-tiles; K=128 in 4 steps
    int wv = tid >> 6;          // wave 0..3
    int ln = tid & 15;          // A-m / B-n / D-col
    int q  = (tid >> 4) & 3;    // quad
    floatx4 C[8];
#pragma unroll
    for (int t = 0; t < 8; t++) {
        float bn = b[t * 16 + ln];
        C[t].x = bn; C[t].y = bn; C[t].z = bn; C[t].w = bn;
    }
#pragma unroll
    for (int kq = 0; kq < 4; kq++) {
        half8 a = *(const half8*)(&gs[wv * 16 + ln][kq * 32 + q * 8]);
#pragma unroll
        for (int t = 0; t < 8; t++) {
            half8 bf = *(const half8*)(Wt + (size_t)(t * 16 + ln) * 128 + kq * 32 + q * 8);
            C[t] = __builtin_amdgcn_mfma_f32_16x16x32_f16(a, bf, C[t], 0, 0, 0);
        }
    }

    // stage relu(D) back into gs (wave-private rows), then coalesced write
    __syncthreads();
#pragma unroll
    for (int t = 0; t < 8; t++) {
#pragma unroll
        for (int reg = 0; reg < 4; reg++) {
            float dv = (reg == 0) ? C[t].x : (reg == 1) ? C[t].y : (reg == 2) ? C[t].z : C[t].w;
            gs[wv * 16 + q * 4 + reg][t * 16 + ln] = (half_t)fmaxf(dv, 0.f);
        }
    }
    __syncthreads();
    int r0 = tid >> 2;                 // row within tile
    int c0 = (tid & 3) * 4;            // int4 offset within row (row = 16 int4)
    int node = n0 + r0;
    if (node < N_NODES) {
        int4* dst = (int4*)(h_out + (size_t)node * 128);
        const int4* srcp = (const int4*)(&gs[r0][0]);
#pragma unroll
        for (int kk = 0; kk < 4; kk++) dst[c0 + kk] = srcp[c0 + kk];
    }
}

// ---------------------------------------------------------------- fused mean-pool + final FC (no atomics)
// block = graph g; 8-way row unroll (8 independent loads in flight); then
// 128x4 FC via LDS reduction.
__global__ __launch_bounds__(128) void k_pool_final(const half_t* __restrict__ h,
                                                    const int* __restrict__ batch,
                                                    const float* __restrict__ Wfc,
                                                    const float* __restrict__ bfc,
                                                    float* __restrict__ out) {
    __shared__ float red[128][4];
    __shared__ int sb_s, eb_s;
    int g = blockIdx.x, t = threadIdx.x;
    if (t == 0) {
        int lo = 0, hi = N_NODES;
        while (lo < hi) { int mid = (lo + hi) >> 1; if (batch[mid] < g) lo = mid + 1; else hi = mid; }
        sb_s = lo;
        hi = N_NODES;
        while (lo < hi) { int mid = (lo + hi) >> 1; if (batch[mid] < g + 1) lo = mid + 1; else hi = mid; }
        eb_s = lo;
    }
    __syncthreads();
    int sb = sb_s, eb = eb_s;
    float a0 = 0.f, a1 = 0.f, a2 = 0.f, a3 = 0.f;
    float a4 = 0.f, a5 = 0.f, a6 = 0.f, a7 = 0.f;
    int n = sb;
    for (; n + 8 <= eb; n += 8) {
        a0 += (float)h[(size_t)(n + 0) * 128 + t];
        a1 += (float)h[(size_t)(n + 1) * 128 + t];
        a2 += (float)h[(size_t)(n + 2) * 128 + t];
        a3 += (float)h[(size_t)(n + 3) * 128 + t];
        a4 += (float)h[(size_t)(n + 4) * 128 + t];
        a5 += (float)h[(size_t)(n + 5) * 128 + t];
        a6 += (float)h[(size_t)(n + 6) * 128 + t];
        a7 += (float)h[(size_t)(n + 7) * 128 + t];
    }
    for (; n < eb; n++) a0 += (float)h[(size_t)n * 128 + t];
    float acc = ((a0 + a1) + (a2 + a3)) + ((a4 + a5) + (a6 + a7));
    float inv = 1.0f / fmaxf((float)(eb - sb), 1.0f);
    float v = acc * inv;
    float4 w = ((const float4*)Wfc)[t];
    red[t][0] = v * w.x; red[t][1] = v * w.y; red[t][2] = v * w.z; red[t][3] = v * w.w;
    __syncthreads();
    for (int s = 64; s > 0; s >>= 1) {
        if (t < s) {
            red[t][0] += red[t + s][0];
            red[t][1] += red[t + s][1];
            red[t][2] += red[t + s][2];
            red[t][3] += red[t + s][3];
        }
        __syncthreads();
    }
    if (t < 4) out[g * 4 + t] = red[0][t] + bfc[t];
}

// ================================================================ launch
extern "C" void kernel_launch(void* const* d_in, const int* in_sizes, int n_in,
                              void* d_out, int out_size, void* d_ws, size_t ws_size,
                              hipStream_t stream) {
    const float* x     = (const float*)d_in[0];
    const int*   ei    = (const int*)d_in[1];
    const int*   row   = ei;             // source
    const int*   col   = ei + N_EDGES;   // target (aggregation side)
    const int*   batch = (const int*)d_in[2];
    const float* W1 = (const float*)d_in[3];
    const float* b1 = (const float*)d_in[4];
    const float* W2 = (const float*)d_in[5];
    const float* b2 = (const float*)d_in[6];
    const float* W3 = (const float*)d_in[7];
    const float* b3 = (const float*)d_in[8];
    const float* W4 = (const float*)d_in[9];
    const float* b4 = (const float*)d_in[10];
    const float* Wfc = (const float*)d_in[11];
    const float* bfc = (const float*)d_in[12];
    float* out = (float*)d_out;

    char* ws = (char*)d_ws;
    size_t off = 0;
    auto take = [&](size_t bytes) -> char* {
        char* p = ws + off;
        off = (off + bytes + 255) & ~(size_t)255;
        return p;
    };
    // deg, cursor contiguous -> one memset
    int*    deg     = (int*)take(N_NODES * 4);
    int*    cursor  = (int*)take(N_NODES * 4);
    size_t  zspan   = (size_t)((char*)cursor + N_NODES * 4 - (char*)deg);
    int*    row_ptr = (int*)take((N_NODES + 1) * 4);
    int*    bsum    = (int*)take(512 * 4);
    float*  dinv    = (float*)take(N_NODES * 4);
    float*  aggx    = (float*)take((size_t)N_NODES * 3 * 4);
    float4* xp      = (float4*)take((size_t)N_NODES * 16);
    int2*   epair   = (int2*)take((size_t)N_EDGES * 8);
    half_t* wt16    = (half_t*)take((size_t)3 * 128 * 128 * 2);
    half_t* bufA    = (half_t*)take((size_t)N_NODES * 128 * 2);
    half_t* bufB    = (half_t*)take((size_t)N_NODES * 128 * 2);

    hipMemsetAsync(deg, 0, zspan, stream);

    k_prep<<<(N_EDGES + 255) / 256, 256, 0, stream>>>(col, deg, x, xp, W2, W3, W4, wt16);
    k_scan1<<<NB_SCAN, 256, 0, stream>>>(deg, row_ptr, bsum, dinv);
    k_scan2<<<1, 512, 0, stream>>>(bsum);
    k_scan3<<<NB_SCAN, 256, 0, stream>>>(row_ptr, bsum);
    k_scatter<<<(N_EDGES + 255) / 256, 256, 0, stream>>>(row, col, row_ptr, cursor,
                                                         dinv, epair);
    k_aggx<<<NB_SCAN, 256, 0, stream>>>(xp, row_ptr, epair, dinv, aggx);
    k_fc1<<<(N_NODES * 32 + 255) / 256, 256, 0, stream>>>(aggx, W1, b1, bufA);

    const int NBA = (N_NODES + 15) / 16;          // k_agg grid
    const int NBM = (N_NODES + TILE - 1) / TILE;  // k_mm grid
    // layer 2: agg(bufA)->bufB ; mm(bufB)->bufA
    k_agg<<<NBA, 256, 0, stream>>>(bufA, row_ptr, epair, dinv, bufB);
    k_mm<<<NBM, 256, 0, stream>>>(bufB, wt16, b2, bufA);
    // layer 3
    k_agg<<<NBA, 256, 0, stream>>>(bufA, row_ptr, epair, dinv, bufB);
    k_mm<<<NBM, 256, 0, stream>>>(bufB, wt16 + 16384, b3, bufA);
    // layer 4
    k_agg<<<NBA, 256, 0, stream>>>(bufA, row_ptr, epair, dinv, bufB);
    k_mm<<<NBM, 256, 0, stream>>>(bufB, wt16 + 32768, b4, bufA);

    // fused mean-pool + FC (no atomics)
    k_pool_final<<<N_GRAPHS, 128, 0, stream>>>(bufA, batch, Wfc, bfc, out);
}

// Round 16
// 382.976 us; speedup vs baseline: 1.1120x; 1.0172x over previous
//
#include <hip/hip_runtime.h>
#include <hip/hip_bf16.h>

#define N_NODES  100000
#define N_EDGES  640000
#define N_GRAPHS 2048
#define HID      128
#define NB_SCAN  391   // ceil(N_NODES/256)
#define TILE     64    // nodes per mm tile

typedef _Float16 half_t;
typedef __attribute__((ext_vector_type(4))) _Float16 half4;
typedef __attribute__((ext_vector_type(8))) _Float16 half8;
typedef __attribute__((ext_vector_type(4))) float floatx4;

// ---------------------------------------------------------------- fused prep: degree + x pack + weight convert
__global__ void k_prep(const int* __restrict__ col, int* __restrict__ deg,
                       const float* __restrict__ x, float4* __restrict__ xp,
                       const float* __restrict__ W2, const float* __restrict__ W3,
                       const float* __restrict__ W4, half_t* __restrict__ Wt) {
    int idx = blockIdx.x * 256 + threadIdx.x;
    if (idx < N_EDGES) atomicAdd(&deg[col[idx]], 1);
    if (idx < N_NODES) xp[idx] = make_float4(x[idx * 3 + 0], x[idx * 3 + 1], x[idx * 3 + 2], 0.f);
    if (idx < 3 * 128 * 128) {
        int l = idx >> 14;
        int e = idx & 16383;
        int cin = e >> 7, cout = e & 127;
        const float* W = (l == 0) ? W2 : ((l == 1) ? W3 : W4);
        Wt[l * 16384 + cout * 128 + cin] = (half_t)W[cin * 128 + cout];
    }
}

// ---------------------------------------------------------------- scan (exclusive prefix sum of deg -> row_ptr) + dinv
__global__ void k_scan1(const int* __restrict__ deg, int* __restrict__ row_ptr,
                        int* __restrict__ bsum, float* __restrict__ dinv) {
    __shared__ int s[256];
    int tid = threadIdx.x;
    int i = blockIdx.x * 256 + tid;
    int d = (i < N_NODES) ? deg[i] : 0;
    if (i < N_NODES) dinv[i] = rsqrtf((float)(d + 1));  // +1 self loop
    s[tid] = d;
    __syncthreads();
    for (int off = 1; off < 256; off <<= 1) {
        int v = (tid >= off) ? s[tid - off] : 0;
        __syncthreads();
        s[tid] += v;
        __syncthreads();
    }
    if (i < N_NODES) row_ptr[i] = s[tid] - d;   // exclusive within block
    if (tid == 255) bsum[blockIdx.x] = s[255];
}

__global__ void k_scan2(int* __restrict__ bsum) {
    __shared__ int s[512];
    int tid = threadIdx.x;
    int v = (tid < NB_SCAN) ? bsum[tid] : 0;
    s[tid] = v;
    __syncthreads();
    for (int off = 1; off < 512; off <<= 1) {
        int u = (tid >= off) ? s[tid - off] : 0;
        __syncthreads();
        s[tid] += u;
        __syncthreads();
    }
    if (tid < NB_SCAN) bsum[tid] = s[tid] - v;  // exclusive block offsets
}

__global__ void k_scan3(int* __restrict__ row_ptr, const int* __restrict__ bsum) {
    int i = blockIdx.x * 256 + threadIdx.x;
    if (i < N_NODES) row_ptr[i] += bsum[blockIdx.x];
    if (i == N_NODES) row_ptr[N_NODES] = N_EDGES;
}

// ---------------------------------------------------------------- CSR scatter: packed (src, weight) int2 -> ONE 8B store
__global__ void k_scatter(const int* __restrict__ row, const int* __restrict__ col,
                          const int* __restrict__ row_ptr, int* __restrict__ cursor,
                          const float* __restrict__ dinv, int2* __restrict__ epair) {
    int e = blockIdx.x * blockDim.x + threadIdx.x;
    if (e >= N_EDGES) return;
    int c = col[e];
    int r = row[e];
    int p = row_ptr[c] + atomicAdd(&cursor[c], 1);
    epair[p] = make_int2(r, __float_as_int(dinv[r] * dinv[c]));
}

// ---------------------------------------------------------------- fused: aggregate x + layer-1 dense -> fp16 h1
// Phase A: thread-per-node 3-channel gather -> LDS. Phase B: 32 lanes/node
// FC from LDS (W1 registers reused across 32 passes).
__global__ __launch_bounds__(256) void k_aggx_fc1(const float4* __restrict__ xp,
                                                  const int* __restrict__ row_ptr,
                                                  const int2* __restrict__ epair,
                                                  const float* __restrict__ dinv,
                                                  const float* __restrict__ W1,
                                                  const float* __restrict__ b1,
                                                  half_t* __restrict__ h) {
    __shared__ float sax[256][3];
    int t = threadIdx.x;
    int nb = blockIdx.x * 256;
    int i = nb + t;
    if (i < N_NODES) {
        float di = dinv[i];
        float sw = di * di;
        float4 xv = xp[i];
        float a0 = sw * xv.x, a1 = sw * xv.y, a2 = sw * xv.z;
        int s = row_ptr[i], e = row_ptr[i + 1];
        int k = s;
        for (; k + 4 <= e; k += 4) {
            int2 pr[4];
#pragma unroll
            for (int r = 0; r < 4; r++) pr[r] = epair[k + r];
            float4 bx[4];
#pragma unroll
            for (int r = 0; r < 4; r++) bx[r] = xp[pr[r].x];
#pragma unroll
            for (int r = 0; r < 4; r++) {
                float w = __int_as_float(pr[r].y);
                a0 += w * bx[r].x;
                a1 += w * bx[r].y;
                a2 += w * bx[r].z;
            }
        }
        for (; k < e; k++) {
            int2 pr = epair[k];
            float w = __int_as_float(pr.y);
            float4 bx = xp[pr.x];
            a0 += w * bx.x;
            a1 += w * bx.y;
            a2 += w * bx.z;
        }
        sax[t][0] = a0; sax[t][1] = a1; sax[t][2] = a2;
    }
    __syncthreads();
    int cq = t & 31, g8 = t >> 5;
    const float4* W14 = (const float4*)W1;
    float4 w0 = W14[cq], w1 = W14[32 + cq], w2 = W14[64 + cq];
    float4 bb = ((const float4*)b1)[cq];
    for (int pass = 0; pass < 32; pass++) {
        int local = pass * 8 + g8;
        int node = nb + local;
        if (node >= N_NODES) break;
        float x0 = sax[local][0], x1 = sax[local][1], x2 = sax[local][2];
        half4 o;
        o.x = (half_t)fmaxf(bb.x + x0 * w0.x + x1 * w1.x + x2 * w2.x, 0.f);
        o.y = (half_t)fmaxf(bb.y + x0 * w0.y + x1 * w1.y + x2 * w2.y, 0.f);
        o.z = (half_t)fmaxf(bb.z + x0 * w0.z + x1 * w1.z + x2 * w2.z, 0.f);
        o.w = (half_t)fmaxf(bb.w + x0 * w0.w + x1 * w1.w + x2 * w2.w, 0.f);
        ((half4*)h)[(size_t)node * 32 + cq] = o;
    }
}

// ---------------------------------------------------------------- LEAN standalone gather: g = Agg(h), fp16 rows
// 16 nodes/block (16 lanes x half8 = 256B row). Pairwise edge loop with pair
// prefetch (4 rows in flight per group). Packed int2 edge metadata.
__global__ __launch_bounds__(256, 8) void k_agg(const half_t* __restrict__ h_in,
                                                const int* __restrict__ row_ptr,
                                                const int2* __restrict__ epair,
                                                const float* __restrict__ dinv,
                                                half_t* __restrict__ g) {
    int tid = threadIdx.x;
    int lane16 = tid & 15;
    int i = blockIdx.x * 16 + (tid >> 4);
    if (i >= N_NODES) return;
    const half8* h8 = (const half8*)h_in;

    float di = dinv[i];
    float sw = di * di;
    half8 v = h8[(size_t)i * 16 + lane16];
    float acc[8];
#pragma unroll
    for (int c = 0; c < 8; c++) acc[c] = sw * (float)v[c];

    int s = row_ptr[i], e = row_ptr[i + 1];
    if (s < e) {
        int em1 = e - 1;
        int2 p0 = epair[s];
        int k1 = min(s + 1, em1);
        int2 p1 = epair[k1];
        float w0 = __int_as_float(p0.y);
        float w1 = (s + 1 < e) ? __int_as_float(p1.y) : 0.f;
        half8 u0 = h8[(size_t)p0.x * 16 + lane16];
        half8 u1 = h8[(size_t)p1.x * 16 + lane16];
        for (int k = s; k < e; k += 2) {
            int k2 = min(k + 2, em1);
            int k3 = min(k + 3, em1);
            int2 p2 = epair[k2];
            int2 p3 = epair[k3];
            float w2 = (k + 2 < e) ? __int_as_float(p2.y) : 0.f;
            float w3 = (k + 3 < e) ? __int_as_float(p3.y) : 0.f;
            half8 n0 = h8[(size_t)p2.x * 16 + lane16];   // next pair in flight
            half8 n1 = h8[(size_t)p3.x * 16 + lane16];
#pragma unroll
            for (int c = 0; c < 8; c++) acc[c] += w0 * (float)u0[c] + w1 * (float)u1[c];
            u0 = n0; u1 = n1; w0 = w2; w1 = w3;
        }
    }
    half8 av;
#pragma unroll
    for (int c = 0; c < 8; c++) av[c] = (half_t)acc[c];
    ((half8*)g)[(size_t)i * 16 + lane16] = av;
}

// ---------------------------------------------------------------- MFMA dense: h_out = relu(g @ W + b)
__global__ __launch_bounds__(256) void k_mm(const half_t* __restrict__ g,
                                            const half_t* __restrict__ Wt,
                                            const float* __restrict__ b,
                                            half_t* __restrict__ h_out) {
    __shared__ half_t gs[TILE][128];  // 16 KB
    int tid = threadIdx.x;
    int n0 = blockIdx.x * TILE;

    // cooperative tile load: row = 128 halves = 256 B = 16 int4; 64 rows = 1024 int4
    const int4* gsrc = (const int4*)(g + (size_t)n0 * 128);
    int4* gdst = (int4*)&gs[0][0];
    for (int idx = tid; idx < TILE * 16; idx += 256) {
        int node = n0 + (idx >> 4);
        int4 vv;
        if (node < N_NODES) vv = gsrc[idx];
        else { vv.x = vv.y = vv.z = vv.w = 0; }
        gdst[idx] = vv;
    }
    __syncthreads();

    // MFMA 64x128x128
    int wv = tid >> 6;          // wave 0..3
    int ln = tid & 15;          // A-m / B-n / D-col
    int q  = (tid >> 4) & 3;    // quad
    floatx4 C[8];
#pragma unroll
    for (int t = 0; t < 8; t++) {
        float bn = b[t * 16 + ln];
        C[t].x = bn; C[t].y = bn; C[t].z = bn; C[t].w = bn;
    }
#pragma unroll
    for (int kq = 0; kq < 4; kq++) {
        half8 a = *(const half8*)(&gs[wv * 16 + ln][kq * 32 + q * 8]);
#pragma unroll
        for (int t = 0; t < 8; t++) {
            half8 bf = *(const half8*)(Wt + (size_t)(t * 16 + ln) * 128 + kq * 32 + q * 8);
            C[t] = __builtin_amdgcn_mfma_f32_16x16x32_f16(a, bf, C[t], 0, 0, 0);
        }
    }

    // stage relu(D) back into gs, then coalesced write
    __syncthreads();
#pragma unroll
    for (int t = 0; t < 8; t++) {
#pragma unroll
        for (int reg = 0; reg < 4; reg++) {
            float dv = (reg == 0) ? C[t].x : (reg == 1) ? C[t].y : (reg == 2) ? C[t].z : C[t].w;
            gs[wv * 16 + q * 4 + reg][t * 16 + ln] = (half_t)fmaxf(dv, 0.f);
        }
    }
    __syncthreads();
    int r0 = tid >> 2;
    int c0 = (tid & 3) * 4;
    int node = n0 + r0;
    if (node < N_NODES) {
        int4* dst = (int4*)(h_out + (size_t)node * 128);
        const int4* srcp = (const int4*)(&gs[r0][0]);
#pragma unroll
        for (int kk = 0; kk < 4; kk++) dst[c0 + kk] = srcp[c0 + kk];
    }
}

// ---------------------------------------------------------------- fused mean-pool + final FC (no atomics, vectorized)
// 16 lanes x half8 (16B/lane) x 8 row-slots -> 8 rows in flight, 8x fewer
// load instrs than channel-per-thread. Slot partials reduced via LDS.
__global__ __launch_bounds__(128) void k_pool_final(const half_t* __restrict__ h,
                                                    const int* __restrict__ batch,
                                                    const float* __restrict__ Wfc,
                                                    const float* __restrict__ bfc,
                                                    float* __restrict__ out) {
    __shared__ float sred[8][128];
    __shared__ float red[128][4];
    __shared__ int sb_s, eb_s;
    int g = blockIdx.x, t = threadIdx.x;
    if (t == 0) {
        int lo = 0, hi = N_NODES;
        while (lo < hi) { int mid = (lo + hi) >> 1; if (batch[mid] < g) lo = mid + 1; else hi = mid; }
        sb_s = lo;
        hi = N_NODES;
        while (lo < hi) { int mid = (lo + hi) >> 1; if (batch[mid] < g + 1) lo = mid + 1; else hi = mid; }
        eb_s = lo;
    }
    __syncthreads();
    int sb = sb_s, eb = eb_s;
    int lane16 = t & 15, slot = t >> 4;
    const half8* h8 = (const half8*)h;
    float acc[8];
#pragma unroll
    for (int c = 0; c < 8; c++) acc[c] = 0.f;
    for (int n = sb + slot; n < eb; n += 8) {
        half8 v = h8[(size_t)n * 16 + lane16];
#pragma unroll
        for (int c = 0; c < 8; c++) acc[c] += (float)v[c];
    }
#pragma unroll
    for (int c = 0; c < 8; c++) sred[slot][lane16 * 8 + c] = acc[c];
    __syncthreads();
    float pv = 0.f;
#pragma unroll
    for (int s2 = 0; s2 < 8; s2++) pv += sred[s2][t];
    float inv = 1.0f / fmaxf((float)(eb - sb), 1.0f);
    float v = pv * inv;
    float4 w = ((const float4*)Wfc)[t];
    red[t][0] = v * w.x; red[t][1] = v * w.y; red[t][2] = v * w.z; red[t][3] = v * w.w;
    __syncthreads();
    for (int s = 64; s > 0; s >>= 1) {
        if (t < s) {
            red[t][0] += red[t + s][0];
            red[t][1] += red[t + s][1];
            red[t][2] += red[t + s][2];
            red[t][3] += red[t + s][3];
        }
        __syncthreads();
    }
    if (t < 4) out[g * 4 + t] = red[0][t] + bfc[t];
}

// ================================================================ launch
extern "C" void kernel_launch(void* const* d_in, const int* in_sizes, int n_in,
                              void* d_out, int out_size, void* d_ws, size_t ws_size,
                              hipStream_t stream) {
    const float* x     = (const float*)d_in[0];
    const int*   ei    = (const int*)d_in[1];
    const int*   row   = ei;             // source
    const int*   col   = ei + N_EDGES;   // target (aggregation side)
    const int*   batch = (const int*)d_in[2];
    const float* W1 = (const float*)d_in[3];
    const float* b1 = (const float*)d_in[4];
    const float* W2 = (const float*)d_in[5];
    const float* b2 = (const float*)d_in[6];
    const float* W3 = (const float*)d_in[7];
    const float* b3 = (const float*)d_in[8];
    const float* W4 = (const float*)d_in[9];
    const float* b4 = (const float*)d_in[10];
    const float* Wfc = (const float*)d_in[11];
    const float* bfc = (const float*)d_in[12];
    float* out = (float*)d_out;

    char* ws = (char*)d_ws;
    size_t off = 0;
    auto take = [&](size_t bytes) -> char* {
        char* p = ws + off;
        off = (off + bytes + 255) & ~(size_t)255;
        return p;
    };
    // deg, cursor contiguous -> one memset
    int*    deg     = (int*)take(N_NODES * 4);
    int*    cursor  = (int*)take(N_NODES * 4);
    size_t  zspan   = (size_t)((char*)cursor + N_NODES * 4 - (char*)deg);
    int*    row_ptr = (int*)take((N_NODES + 1) * 4);
    int*    bsum    = (int*)take(512 * 4);
    float*  dinv    = (float*)take(N_NODES * 4);
    float4* xp      = (float4*)take((size_t)N_NODES * 16);
    int2*   epair   = (int2*)take((size_t)N_EDGES * 8);
    half_t* wt16    = (half_t*)take((size_t)3 * 128 * 128 * 2);
    half_t* bufA    = (half_t*)take((size_t)N_NODES * 128 * 2);
    half_t* bufB    = (half_t*)take((size_t)N_NODES * 128 * 2);

    hipMemsetAsync(deg, 0, zspan, stream);

    k_prep<<<(N_EDGES + 255) / 256, 256, 0, stream>>>(col, deg, x, xp, W2, W3, W4, wt16);
    k_scan1<<<NB_SCAN, 256, 0, stream>>>(deg, row_ptr, bsum, dinv);
    k_scan2<<<1, 512, 0, stream>>>(bsum);
    k_scan3<<<NB_SCAN, 256, 0, stream>>>(row_ptr, bsum);
    k_scatter<<<(N_EDGES + 255) / 256, 256, 0, stream>>>(row, col, row_ptr, cursor,
                                                         dinv, epair);
    k_aggx_fc1<<<NB_SCAN, 256, 0, stream>>>(xp, row_ptr, epair, dinv, W1, b1, bufA);

    const int NBA = (N_NODES + 15) / 16;          // k_agg grid
    const int NBM = (N_NODES + TILE - 1) / TILE;  // k_mm grid
    // layer 2: agg(bufA)->bufB ; mm(bufB)->bufA
    k_agg<<<NBA, 256, 0, stream>>>(bufA, row_ptr, epair, dinv, bufB);
    k_mm<<<NBM, 256, 0, stream>>>(bufB, wt16, b2, bufA);
    // layer 3
    k_agg<<<NBA, 256, 0, stream>>>(bufA, row_ptr, epair, dinv, bufB);
    k_mm<<<NBM, 256, 0, stream>>>(bufB, wt16 + 16384, b3, bufA);
    // layer 4
    k_agg<<<NBA, 256, 0, stream>>>(bufA, row_ptr, epair, dinv, bufB);
    k_mm<<<NBM, 256, 0, stream>>>(bufB, wt16 + 32768, b4, bufA);

    // fused mean-pool + FC (no atomics)
    k_pool_final<<<N_GRAPHS, 128, 0, stream>>>(bufA, batch, Wfc, bfc, out);
}